// Round 1
// 287.505 us; speedup vs baseline: 1.0582x; 1.0582x over previous
//
#include <hip/hip_runtime.h>

typedef unsigned int   uint;
typedef unsigned short ushort;
typedef short bf16x8 __attribute__((ext_vector_type(8)));
typedef float f32x4  __attribute__((ext_vector_type(4)));

// Problem constants
constexpr int Bm   = 512;   // molecules
constexpr int Aa   = 128;   // atoms / molecule
constexpr int Ee   = 256;   // directed bonds / molecule
constexpr int Kk   = 6;     // incoming gathered
constexpr int AFD  = 133;
constexpr int FD   = 147;   // 133+14
constexpr int Hh   = 128;
constexpr int CATD = 261;   // 133+128
constexpr int KWI  = 192;   // Wi_b row stride (147 real + 45 zero)
constexpr int KWO  = 320;   // Wo_b row stride: [0,133) atomf cols, [133,192) zero, [192,320) m2a cols
constexpr int MST  = 136;   // msg LDS row stride (bf16): 128 + 8 pad -> 4-bank row step
constexpr int SST  = 72;    // staging LDS row stride (bf16): 64 + 8 pad

// ---- bf16 helpers ----------------------------------------------------------
__device__ __forceinline__ ushort f2b(float f) {
    uint u = __float_as_uint(f);
    u += 0x7FFFu + ((u >> 16) & 1u);
    return (ushort)(u >> 16);
}
__device__ __forceinline__ uint f2b2(float x, float y) {
    return (uint)f2b(x) | ((uint)f2b(y) << 16);
}
__device__ __forceinline__ float2 b2f2(uint p) {
    float2 r;
    r.x = __uint_as_float(p << 16);
    r.y = __uint_as_float(p & 0xFFFF0000u);
    return r;
}

// sum 6 post-relu bf16 rows (16B slices) from LDS, repack to an MFMA A-frag
__device__ __forceinline__ bf16x8 gsum6(const ushort* src, const int* mr, int ko) {
    float2 s0 = {0.f, 0.f}, s1 = {0.f, 0.f}, s2 = {0.f, 0.f}, s3 = {0.f, 0.f};
#pragma unroll
    for (int k = 0; k < Kk; ++k) {
        uint4 m = *(const uint4*)&src[mr[k] + ko];
        float2 a = b2f2(m.x); s0.x += a.x; s0.y += a.y;
        float2 b = b2f2(m.y); s1.x += b.x; s1.y += b.y;
        float2 d = b2f2(m.z); s2.x += d.x; s2.y += d.y;
        float2 e = b2f2(m.w); s3.x += e.x; s3.y += e.y;
    }
    uint4 o;
    o.x = f2b2(s0.x, s0.y); o.y = f2b2(s1.x, s1.y);
    o.z = f2b2(s2.x, s2.y); o.w = f2b2(s3.x, s3.y);
    bf16x8 r;
    __builtin_memcpy(&r, &o, 16);
    return r;
}

// ---------------------------------------------------------------------------
// Weight prep: fp32 -> padded bf16 (tiny; runs once, concurrent with k_scan)
// ---------------------------------------------------------------------------
__global__ __launch_bounds__(256) void k_prep_w(const float* __restrict__ Wi,
                                                const float* __restrict__ Wh,
                                                const float* __restrict__ Wo,
                                                ushort* __restrict__ Wi_b,
                                                ushort* __restrict__ Wh_b,
                                                ushort* __restrict__ Wo_b) {
    const int h = blockIdx.x, t = threadIdx.x;
    for (int c = t; c < KWI; c += 256)
        Wi_b[h * KWI + c] = f2b(c < FD ? Wi[h * FD + c] : 0.f);
    for (int c = t; c < Hh; c += 256)
        Wh_b[h * Hh + c] = f2b(Wh[h * Hh + c]);
    for (int c = t; c < KWO; c += 256) {
        float v = 0.f;
        if (c < AFD)       v = Wo[h * CATD + c];
        else if (c >= 192) v = Wo[h * CATD + AFD + (c - 192)];
        Wo_b[h * KWO + c] = f2b(v);
    }
}

__global__ __launch_bounds__(512) void k_scan(const int* __restrict__ ml,
                                              int* __restrict__ pfx) {
    __shared__ int s[512];
    int t = threadIdx.x;
    s[t] = ml[t];
    __syncthreads();
    for (int off = 1; off < 512; off <<= 1) {
        int v = (t >= off) ? s[t - off] : 0;
        __syncthreads();
        s[t] += v;
        __syncthreads();
    }
    pfx[t + 1] = s[t];
    if (t == 0) pfx[0] = 0;
}

// ---------------------------------------------------------------------------
// Fused DMPNN: one block = one molecule. msg state lives in LDS end-to-end.
//   Phase 1: inp = fini @ Wi^T           (fini fp32 staged+converted inline)
//            msg0 = relu(inp); inp kept pre-act in 32 packed VGPRs/lane
//   Phase 2: 2 hops: msg_dst = relu(inp + gather6(msg_src) @ Wh^T)
//   Phase 3: readout: relu([atomf | m2a] @ Wo^T + bo), masked packed store
// 8 waves, wave w owns rows [w*32, w*32+32) (bond phases) / [w*16,..) (atoms).
// ---------------------------------------------------------------------------
__global__ __launch_bounds__(512, 2) void k_fused(
        const float* __restrict__ atomf,
        const float* __restrict__ fini,
        const int*   __restrict__ a2ib,
        const int*   __restrict__ mapping,
        const ushort* __restrict__ Wi_b,
        const ushort* __restrict__ Wh_b,
        const ushort* __restrict__ Wo_b,
        const float* __restrict__ bo,
        const int*   __restrict__ mol_lens,
        const int*   __restrict__ pfx,
        float* __restrict__ out,
        float* __restrict__ cmask) {
    __shared__ ushort msg0[Ee * MST];      // 69,632 B
    __shared__ ushort msg1[Ee * MST];      // 69,632 B (also staging buffer)
    __shared__ int    map_s[Ee * Kk];      //  6,144 B
    __shared__ int    a2_s[Aa * Kk];       //  3,072 B   -> 148,480 B total

    const int b    = blockIdx.x;
    const int tid  = threadIdx.x;
    const int wave = tid >> 6;
    const int lane = tid & 63;
    const int l15  = lane & 15, quad = lane >> 4;

    for (int i = tid; i < Ee * Kk; i += 512) map_s[i] = mapping[b * Ee * Kk + i];
    for (int i = tid; i < Aa * Kk; i += 512) a2_s[i]  = a2ib[b * Aa * Kk + i];
    const int len = mol_lens[b];
    if (tid < Aa) cmask[b * Aa + tid] = (tid < len) ? 1.0f : 0.0f;

    f32x4 acc[2][8];
#pragma unroll
    for (int i = 0; i < 2; ++i)
#pragma unroll
        for (int j = 0; j < 8; ++j) acc[i][j] = (f32x4){0.f, 0.f, 0.f, 0.f};

    // ---- Phase 1: inp = fini @ Wi^T ------------------------------------
    const float* fsrc = fini + (size_t)b * Ee * FD;
    for (int c = 0; c < 3; ++c) {
        for (int idx = tid; idx < Ee * 16; idx += 512) {
            int r = idx >> 4, gg = idx & 15;
            int c0 = c * 64 + gg * 4;
            const float* sp = fsrc + (size_t)r * FD + c0;
            float v0 = (c0 + 0 < FD) ? sp[0] : 0.f;
            float v1 = (c0 + 1 < FD) ? sp[1] : 0.f;
            float v2 = (c0 + 2 < FD) ? sp[2] : 0.f;
            float v3 = (c0 + 3 < FD) ? sp[3] : 0.f;
            uint2 p;
            p.x = f2b2(v0, v1);
            p.y = f2b2(v2, v3);
            *(uint2*)&msg1[r * SST + gg * 4] = p;
        }
        __syncthreads();
#pragma unroll
        for (int ks = 0; ks < 2; ++ks) {
            const int ko = ks * 32 + quad * 8;
            bf16x8 bf[8], af[2];
#pragma unroll
            for (int j = 0; j < 8; ++j)
                bf[j] = *(const bf16x8*)&Wi_b[(j * 16 + l15) * KWI + c * 64 + ko];
#pragma unroll
            for (int i = 0; i < 2; ++i)
                af[i] = *(const bf16x8*)&msg1[(wave * 32 + i * 16 + l15) * SST + ko];
#pragma unroll
            for (int i = 0; i < 2; ++i)
#pragma unroll
                for (int j = 0; j < 8; ++j)
                    acc[i][j] = __builtin_amdgcn_mfma_f32_16x16x32_bf16(
                        af[i], bf[j], acc[i][j], 0, 0, 0);
        }
        __syncthreads();
    }

    // inp -> packed regs (pre-act); msg0 = relu(inp)
    uint2 inp_pk[2][8];
#pragma unroll
    for (int i = 0; i < 2; ++i)
#pragma unroll
        for (int j = 0; j < 8; ++j) {
            f32x4 a4 = acc[i][j];
            uint2 p;
            p.x = f2b2(a4[0], a4[1]);
            p.y = f2b2(a4[2], a4[3]);
            inp_pk[i][j] = p;
            int col = j * 16 + l15;
#pragma unroll
            for (int reg = 0; reg < 4; ++reg) {
                int row = wave * 32 + i * 16 + quad * 4 + reg;
                float v = a4[reg] > 0.f ? a4[reg] : 0.f;
                msg0[row * MST + col] = f2b(v);
            }
        }
    __syncthreads();

    // ---- Phase 2: two message-passing hops ------------------------------
#pragma unroll
    for (int h = 0; h < 2; ++h) {
        const ushort* src = h ? msg1 : msg0;
        ushort*       dst = h ? msg0 : msg1;
        int mr[2][Kk];
#pragma unroll
        for (int i = 0; i < 2; ++i) {
            int row = wave * 32 + i * 16 + l15;
#pragma unroll
            for (int k = 0; k < Kk; ++k) mr[i][k] = map_s[row * Kk + k] * MST;
        }
#pragma unroll
        for (int i = 0; i < 2; ++i)
#pragma unroll
            for (int j = 0; j < 8; ++j) acc[i][j] = (f32x4){0.f, 0.f, 0.f, 0.f};
#pragma unroll
        for (int ks = 0; ks < 4; ++ks) {
            const int ko = ks * 32 + quad * 8;
            bf16x8 bf[8], af[2];
#pragma unroll
            for (int j = 0; j < 8; ++j)
                bf[j] = *(const bf16x8*)&Wh_b[(j * 16 + l15) * Hh + ko];
#pragma unroll
            for (int i = 0; i < 2; ++i) af[i] = gsum6(src, mr[i], ko);
#pragma unroll
            for (int i = 0; i < 2; ++i)
#pragma unroll
                for (int j = 0; j < 8; ++j)
                    acc[i][j] = __builtin_amdgcn_mfma_f32_16x16x32_bf16(
                        af[i], bf[j], acc[i][j], 0, 0, 0);
        }
#pragma unroll
        for (int i = 0; i < 2; ++i)
#pragma unroll
            for (int j = 0; j < 8; ++j) {
                float2 lo = b2f2(inp_pk[i][j].x);
                float2 hi = b2f2(inp_pk[i][j].y);
                float v[4];
                v[0] = lo.x + acc[i][j][0];
                v[1] = lo.y + acc[i][j][1];
                v[2] = hi.x + acc[i][j][2];
                v[3] = hi.y + acc[i][j][3];
                int col = j * 16 + l15;
#pragma unroll
                for (int reg = 0; reg < 4; ++reg) {
                    int row = wave * 32 + i * 16 + quad * 4 + reg;
                    float r = v[reg] > 0.f ? v[reg] : 0.f;
                    dst[row * MST + col] = f2b(r);
                }
            }
        __syncthreads();
    }
    // final msg (post-relu) now in msg0; msg1 free for staging

    // ---- Phase 3: readout ----------------------------------------------
    f32x4 ro[8];
#pragma unroll
    for (int j = 0; j < 8; ++j) ro[j] = (f32x4){0.f, 0.f, 0.f, 0.f};

    const float* asrc = atomf + (size_t)b * Aa * AFD;
    for (int c = 0; c < 3; ++c) {               // atomf region, K cols [0,192)
        for (int idx = tid; idx < Aa * 16; idx += 512) {
            int r = idx >> 4, gg = idx & 15;
            int c0 = c * 64 + gg * 4;
            const float* sp = asrc + (size_t)r * AFD + c0;
            float v0 = (c0 + 0 < AFD) ? sp[0] : 0.f;
            float v1 = (c0 + 1 < AFD) ? sp[1] : 0.f;
            float v2 = (c0 + 2 < AFD) ? sp[2] : 0.f;
            float v3 = (c0 + 3 < AFD) ? sp[3] : 0.f;
            uint2 p;
            p.x = f2b2(v0, v1);
            p.y = f2b2(v2, v3);
            *(uint2*)&msg1[r * SST + gg * 4] = p;
        }
        __syncthreads();
#pragma unroll
        for (int ks = 0; ks < 2; ++ks) {
            const int ko = ks * 32 + quad * 8;
            bf16x8 a0 = *(const bf16x8*)&msg1[(wave * 16 + l15) * SST + ko];
            bf16x8 bf[8];
#pragma unroll
            for (int j = 0; j < 8; ++j)
                bf[j] = *(const bf16x8*)&Wo_b[(j * 16 + l15) * KWO + c * 64 + ko];
#pragma unroll
            for (int j = 0; j < 8; ++j)
                ro[j] = __builtin_amdgcn_mfma_f32_16x16x32_bf16(a0, bf[j], ro[j], 0, 0, 0);
        }
        __syncthreads();
    }
    {                                           // m2a gather region, K cols [192,320)
        int ar[Kk];
        int row = wave * 16 + l15;
#pragma unroll
        for (int k = 0; k < Kk; ++k) ar[k] = a2_s[row * Kk + k] * MST;
#pragma unroll
        for (int ks = 0; ks < 4; ++ks) {
            const int ko = ks * 32 + quad * 8;
            bf16x8 a0 = gsum6(msg0, ar, ko);
            bf16x8 bf[8];
#pragma unroll
            for (int j = 0; j < 8; ++j)
                bf[j] = *(const bf16x8*)&Wo_b[(j * 16 + l15) * KWO + 192 + ko];
#pragma unroll
            for (int j = 0; j < 8; ++j)
                ro[j] = __builtin_amdgcn_mfma_f32_16x16x32_bf16(a0, bf[j], ro[j], 0, 0, 0);
        }
    }

    const int base = pfx[b];
#pragma unroll
    for (int j = 0; j < 8; ++j) {
        int col = j * 16 + l15;
        float bv = bo[col];
#pragma unroll
        for (int reg = 0; reg < 4; ++reg) {
            int a = wave * 16 + quad * 4 + reg;
            if (a < len) {
                float v = ro[j][reg] + bv;
                out[(size_t)(base + a) * Hh + col] = v > 0.f ? v : 0.f;
            }
        }
    }
}

// ---------------------------------------------------------------------------
extern "C" void kernel_launch(void* const* d_in, const int* in_sizes, int n_in,
                              void* d_out, int out_size, void* d_ws, size_t ws_size,
                              hipStream_t stream) {
    const float* atom_feature = (const float*)d_in[0];
    const float* f_ini        = (const float*)d_in[1];
    const int*   a2ib         = (const int*)d_in[2];
    const int*   mapping      = (const int*)d_in[3];
    const int*   mol_lens     = (const int*)d_in[5];
    const float* Wi           = (const float*)d_in[6];
    const float* Wh           = (const float*)d_in[7];
    const float* Wo           = (const float*)d_in[8];
    const float* bo           = (const float*)d_in[9];
    float* out = (float*)d_out;

    ushort* Wi_b = (ushort*)d_ws;
    ushort* Wh_b = Wi_b + 128 * KWI;
    ushort* Wo_b = Wh_b + 128 * Hh;
    int*    pfx  = (int*)(Wo_b + 128 * KWO);

    float* cmask = out + ((size_t)out_size - (size_t)Bm * Aa);

    k_prep_w<<<128, 256, 0, stream>>>(Wi, Wh, Wo, Wi_b, Wh_b, Wo_b);
    k_scan  <<<1, 512, 0, stream>>>(mol_lens, pfx);
    k_fused <<<Bm, 512, 0, stream>>>(atom_feature, f_ini, a2ib, mapping,
                                     Wi_b, Wh_b, Wo_b, bo, mol_lens, pfx,
                                     out, cmask);
}